// Round 1
// baseline (248.178 us; speedup 1.0000x reference)
//
#include <hip/hip_runtime.h>
#include <stdint.h>

typedef unsigned long long u64;

#define Bn 4
#define CINn 32
#define Hn 64
#define Wn 64
#define Sn 4096          // 64*64
#define KCn 32
#define Mn 16
#define COUTn 32
#define AREAn 9
#define Fn 288           // CIN*AREA
#define NITER 10
#define FXSCALE 4294967296.0   // 2^32 fixed-point scale for deterministic sums
#define SPLITn 4

static __device__ __forceinline__ float relu_(float v){ return v > 0.f ? v : 0.f; }
static __device__ __forceinline__ float sigm_(float v){ return 1.f / (1.f + __expf(-v) * 0.f + expf(-v) * 1.f); }
// note: use precise expf (not __expf) for sigmoid to track the reference closely
static __device__ __forceinline__ float sigmoid_(float v){ return 1.f / (1.f + expf(-v)); }

// ---------------------------------------------------------------------------
// K1: feat[b][c][p] = mean of 3x3 zero-padded neighborhood / 9. Also zeroes
// the fixed-point accumulators (accum[0..2]) so k_assign iter0 starts clean.
// ---------------------------------------------------------------------------
__global__ __launch_bounds__(256) void k_feat(const float* __restrict__ x,
                                              float* __restrict__ feat,
                                              u64* __restrict__ gsum,
                                              unsigned* __restrict__ gcnt){
    int g = blockIdx.x * 256 + threadIdx.x;          // [0, B*CIN*S)
    if (g < 3 * Bn * KCn * CINn) gsum[g] = 0ull;
    if (g < 3 * Bn * KCn)        gcnt[g] = 0u;
    int p = g & (Sn - 1);
    int c = (g >> 12) & (CINn - 1);
    int b = g >> 17;
    int y = p >> 6, xx = p & 63;
    const float* xc = x + ((size_t)(b * CINn + c) << 12);
    float s = 0.f;
    #pragma unroll
    for (int i = 0; i < 3; ++i){
        int yy = y + i - 1;
        if (yy < 0 || yy >= Hn) continue;
        #pragma unroll
        for (int j = 0; j < 3; ++j){
            int xj = xx + j - 1;
            if (xj < 0 || xj >= Wn) continue;
            s += xc[(yy << 6) + xj];
        }
    }
    feat[g] = s * (1.f / 9.f);
}

// ---------------------------------------------------------------------------
// K2: one Lloyd iteration (launched 11x; iter==10 = final assignment only).
// Phase A: every block redundantly finalizes centroids c_t from the previous
//          iteration's fixed-point sums (deterministic). tile0 persists c_t to
//          global (for next iter's empty-cluster fallback -- value-race-free
//          because for empty clusters c_t == c_{t-1}) and zeroes accum[t+1].
// Phase B: assignment with the reference formula f2 - 2*dot + c2, first-min.
// Phase C: LDS fixed-point pre-reduction, then integer global atomics.
// ---------------------------------------------------------------------------
__global__ __launch_bounds__(256) void k_assign(const float* __restrict__ feat,
                                                float* __restrict__ gcent,
                                                u64* __restrict__ gsum,
                                                unsigned* __restrict__ gcnt,
                                                int* __restrict__ idx,
                                                float* __restrict__ idxf,
                                                int iter){
    __shared__ float cent[KCn][CINn];
    __shared__ float c2[KCn];
    __shared__ u64   lsum[KCn][CINn];
    __shared__ unsigned lcnt[KCn];

    int tid  = threadIdx.x;
    int b    = blockIdx.x >> 4;
    int tile = blockIdx.x & 15;
    int prev = (iter + 2) % 3;
    int cur  = iter % 3;
    int nxt  = (iter + 1) % 3;

    for (int e = tid; e < KCn * CINn; e += 256){
        int k = e >> 5, c = e & 31;
        float v;
        if (iter == 0){
            v = feat[(b * CINn + c) * Sn + k * (Sn / KCn)];   // c0 = feat[k*128]
        } else {
            u64 svu     = gsum[((prev * Bn + b) * KCn + k) * CINn + c];
            unsigned cn = gcnt[(prev * Bn + b) * KCn + k];
            if (cn > 0) v = (float)((double)(long long)svu / ((double)cn * FXSCALE));
            else        v = gcent[(b * KCn + k) * CINn + c];
        }
        cent[k][c] = v;
        lsum[k][c] = 0ull;
        if (tile == 0){
            gcent[(b * KCn + k) * CINn + c] = v;
            gsum[((nxt * Bn + b) * KCn + k) * CINn + c] = 0ull;
        }
    }
    for (int e = tid; e < KCn; e += 256){
        lcnt[e] = 0u;
        if (tile == 0) gcnt[(nxt * Bn + b) * KCn + e] = 0u;
    }
    __syncthreads();
    if (tid < KCn){
        float s = 0.f;
        #pragma unroll
        for (int c = 0; c < CINn; ++c) s += cent[tid][c] * cent[tid][c];
        c2[tid] = s;
    }
    __syncthreads();

    int p = (tile << 8) | tid;
    float fv[CINn];
    #pragma unroll
    for (int c = 0; c < CINn; ++c) fv[c] = feat[(b * CINn + c) * Sn + p];
    float f2 = 0.f;
    #pragma unroll
    for (int c = 0; c < CINn; ++c) f2 = fmaf(fv[c], fv[c], f2);

    float best = 3.402823466e38f; int bi = 0;
    #pragma unroll 4
    for (int k = 0; k < KCn; ++k){
        float dot = 0.f;
        #pragma unroll
        for (int c = 0; c < CINn; ++c) dot = fmaf(fv[c], cent[k][c], dot);
        float d = f2 - 2.f * dot + c2[k];
        if (d < best){ best = d; bi = k; }   // strict < == first-min tie break
    }

    if (iter == NITER){
        idx[b * Sn + p]  = bi;
        idxf[b * Sn + p] = (float)bi;
        return;
    }

    atomicAdd(&lcnt[bi], 1u);
    #pragma unroll
    for (int c = 0; c < CINn; ++c){
        long long q = llrint((double)fv[c] * FXSCALE);
        atomicAdd(&lsum[bi][c], (u64)q);
    }
    __syncthreads();
    for (int e = tid; e < KCn * CINn; e += 256){
        int k = e >> 5, c = e & 31;
        u64 v = lsum[k][c];
        if (v) atomicAdd(&gsum[((cur * Bn + b) * KCn + k) * CINn + c], v);
    }
    if (tid < KCn){
        unsigned v = lcnt[tid];
        if (v) atomicAdd(&gcnt[(cur * Bn + b) * KCn + tid], v);
    }
}

// ---------------------------------------------------------------------------
// K3: deterministic stable counting sort of pixels by final cluster id.
// One block per batch; per-thread LDS histograms, serial-per-k scans.
// ---------------------------------------------------------------------------
__global__ __launch_bounds__(256) void k_sort(const int* __restrict__ idx,
                                              int* __restrict__ sorted,
                                              int* __restrict__ offs){
    int b = blockIdx.x, tid = threadIdx.x;
    __shared__ unsigned hist[256][KCn];   // 32 KiB
    __shared__ unsigned cnts[KCn];
    __shared__ unsigned baseK[KCn + 1];
    #pragma unroll
    for (int k = 0; k < KCn; ++k) hist[tid][k] = 0u;
    int p0 = tid * 16;
    int myk[16];
    #pragma unroll
    for (int i = 0; i < 16; ++i){
        int k = idx[b * Sn + p0 + i];
        myk[i] = k;
        hist[tid][k]++;
    }
    __syncthreads();
    if (tid < KCn){
        unsigned run = 0;
        for (int t = 0; t < 256; ++t){ unsigned v = hist[t][tid]; hist[t][tid] = run; run += v; }
        cnts[tid] = run;
    }
    __syncthreads();
    if (tid == 0){
        unsigned acc = 0;
        for (int k = 0; k < KCn; ++k){ baseK[k] = acc; acc += cnts[k]; }
        baseK[KCn] = acc;
    }
    __syncthreads();
    if (tid <= KCn) offs[b * (KCn + 1) + tid] = (int)baseK[tid];
    #pragma unroll
    for (int i = 0; i < 16; ++i){
        int k = myk[i];
        unsigned pos = baseK[k] + hist[tid][k];
        hist[tid][k]++;
        sorted[b * Sn + pos] = p0 + i;
    }
}

// ---------------------------------------------------------------------------
// K4: per-cluster patch means. Block = (b,k); thread = feature f (c,a).
// Sequential fp32 sum in ascending pixel order (deterministic).
// ---------------------------------------------------------------------------
__global__ __launch_bounds__(320) void k_segsum(const float* __restrict__ x,
                                                const int* __restrict__ sorted,
                                                const int* __restrict__ offs,
                                                float* __restrict__ centp){
    int bk = blockIdx.x; int b = bk >> 5; int k = bk & 31;
    int tid = threadIdx.x;
    int f = tid < Fn ? tid : (Fn - 1);
    int off0 = offs[b * (KCn + 1) + k];
    int n    = offs[b * (KCn + 1) + k + 1] - off0;
    int c = f / 9, a = f - c * 9;
    int di = a / 3 - 1, dj = a % 3 - 1;
    const float* xc = x + ((size_t)(b * CINn + c) << 12);
    const int* plist = sorted + b * Sn + off0;
    __shared__ int pl[320];
    float sum = 0.f;
    for (int base = 0; base < n; base += 320){
        int m = min(320, n - base);
        __syncthreads();
        if (tid < m) pl[tid] = plist[base + tid];
        __syncthreads();
        #pragma unroll 4
        for (int i = 0; i < m; ++i){
            int p = pl[i];
            int y = (p >> 6) + di, xx = (p & 63) + dj;
            float v = (y >= 0 && y < Hn && xx >= 0 && xx < Wn) ? xc[(y << 6) + xx] : 0.f;
            sum += v;
        }
    }
    if (tid < Fn) centp[(b * KCn + k) * Fn + f] = sum / (float)max(n, 1);
}

// ---------------------------------------------------------------------------
// K5: both MLP branches + sigmoid heads + bias head. Block = batch, 512 thr.
// ---------------------------------------------------------------------------
__global__ __launch_bounds__(512) void k_mlp(const float* __restrict__ centp,
        const float* __restrict__ Wh1, const float* __restrict__ bh1,
        const float* __restrict__ Wh2, const float* __restrict__ bh2,
        const float* __restrict__ Wa,  const float* __restrict__ ba,
        const float* __restrict__ Wc,  const float* __restrict__ bc,
        const float* __restrict__ Wo,  const float* __restrict__ bo,
        const float* __restrict__ Wb1, const float* __restrict__ bb1,
        const float* __restrict__ Wb2, const float* __restrict__ bb2,
        const float* __restrict__ Wb3, const float* __restrict__ bb3,
        float* __restrict__ wcin, float* __restrict__ warea,
        float* __restrict__ wcout, float* __restrict__ biasb){
    int b = blockIdx.x, tid = threadIdx.x;
    int k = tid >> 4, j = tid & 15;
    __shared__ float centL[KCn * Fn];     // 36 KiB
    __shared__ float h1[KCn][Mn], hb1s[KCn][Mn];
    __shared__ float kf[KCn][Mn], hb2[KCn][Mn];
    for (int e = tid; e < KCn * Fn; e += 512) centL[e] = centp[b * KCn * Fn + e];
    __syncthreads();
    {
        float a1 = bh1[j], a2 = bb1[j];
        const float* cr = centL + k * Fn;
        for (int f = 0; f < Fn; ++f){
            float cv = cr[f];
            a1 = fmaf(cv, Wh1[f * Mn + j], a1);
            a2 = fmaf(cv, Wb1[f * Mn + j], a2);
        }
        h1[k][j]   = relu_(a1);
        hb1s[k][j] = relu_(a2);
    }
    __syncthreads();
    {
        float a1 = bh2[j], a2 = bb2[j];
        #pragma unroll
        for (int i = 0; i < Mn; ++i){
            a1 = fmaf(h1[k][i],   Wh2[i * Mn + j], a1);
            a2 = fmaf(hb1s[k][i], Wb2[i * Mn + j], a2);
        }
        kf[k][j]  = relu_(a1);
        hb2[k][j] = relu_(a2);
    }
    __syncthreads();
    for (int e = tid; e < KCn * COUTn; e += 512){
        int kk = e >> 5, o = e & 31;
        float s1 = bc[o], s2 = bo[o], s3 = bb3[o];
        #pragma unroll
        for (int i = 0; i < Mn; ++i){
            float kv = kf[kk][i];
            s1 = fmaf(kv, Wc[i * COUTn + o], s1);
            s2 = fmaf(kv, Wo[i * COUTn + o], s2);
            s3 = fmaf(hb2[kk][i], Wb3[i * COUTn + o], s3);
        }
        wcin [(b * KCn + kk) * CINn  + o] = sigmoid_(s1);
        wcout[(b * KCn + kk) * COUTn + o] = sigmoid_(s2);
        biasb[(b * KCn + kk) * COUTn + o] = s3;
    }
    if (tid < KCn * AREAn){
        int kk = tid / 9, a = tid - kk * 9;
        float s = ba[a];
        #pragma unroll
        for (int i = 0; i < Mn; ++i) s = fmaf(kf[kk][i], Wa[i * AREAn + a], s);
        warea[(b * KCn + kk) * AREAn + a] = sigmoid_(s);
    }
}

// ---------------------------------------------------------------------------
// K6: grouped matmul. Block = (b, k, split). Builds the modulated 288x32
// kernel slice transposed in LDS (row pad 292 to dodge stride-32 bank alias),
// stages 8 patches/round, float4 inner loop with 4 accumulators.
// ---------------------------------------------------------------------------
__global__ __launch_bounds__(256) void k_out(const float* __restrict__ x,
                                             const int* __restrict__ sorted,
                                             const int* __restrict__ offs,
                                             const float* __restrict__ wcin,
                                             const float* __restrict__ warea,
                                             const float* __restrict__ wcout,
                                             const float* __restrict__ biasb,
                                             const float* __restrict__ kern0,
                                             float* __restrict__ out){
    int g  = blockIdx.x;
    int sp = g & (SPLITn - 1);
    int k  = (g >> 2) & 31;
    int b  = g >> 7;
    int tid = threadIdx.x;

    __shared__ float kernT[COUTn][292];   // 36.5 KiB, transposed [o][f]
    __shared__ float biasL[COUTn];
    __shared__ float wcl[CINn], wal[16], wol[COUTn];
    __shared__ float patchL[8 * Fn];      // 9 KiB
    __shared__ int   pix[8];

    if (tid < 32)                 wcl[tid]       = wcin [(b * KCn + k) * CINn  + tid];
    else if (tid < 64)            wol[tid - 32]  = wcout[(b * KCn + k) * COUTn + tid - 32];
    else if (tid < 64 + AREAn)    wal[tid - 64]  = warea[(b * KCn + k) * AREAn + tid - 64];
    else if (tid >= 96 && tid < 128) biasL[tid - 96] = biasb[(b * KCn + k) * COUTn + tid - 96];
    __syncthreads();

    for (int e = tid; e < Fn * COUTn; e += 256){
        int f = e >> 5, o = e & 31;
        int c = f / 9, a = f - c * 9;
        kernT[o][f] = wcl[c] * wal[a] * wol[o] * kern0[e];
    }

    int off0 = offs[b * (KCn + 1) + k];
    int n    = offs[b * (KCn + 1) + k + 1] - off0;
    int per  = (n + SPLITn - 1) >> 2;
    int i0 = sp * per, i1 = min(n, i0 + per);
    __syncthreads();

    for (int base = i0; base < i1; base += 8){
        int m = min(8, i1 - base);
        if (tid < 8) pix[tid] = (tid < m) ? sorted[b * Sn + off0 + base + tid] : -1;
        __syncthreads();
        for (int v = tid; v < 8 * Fn; v += 256){
            int pl = v / Fn, f = v - pl * Fn;
            int p = pix[pl];
            float val = 0.f;
            if (p >= 0){
                int c = f / 9, a = f - c * 9;
                int y = (p >> 6) + a / 3 - 1, xx = (p & 63) + (a % 3) - 1;
                if (y >= 0 && y < Hn && xx >= 0 && xx < Wn)
                    val = x[((size_t)(b * CINn + c) << 12) + (y << 6) + xx];
            }
            patchL[v] = val;
        }
        __syncthreads();
        int pl = tid >> 5, o = tid & 31;
        if (pl < m){
            const float* pr = patchL + pl * Fn;
            const float* kr = &kernT[o][0];
            float a0 = 0.f, a1 = 0.f, a2 = 0.f, a3 = 0.f;
            #pragma unroll
            for (int f = 0; f < Fn; f += 4){
                float4 pv = *reinterpret_cast<const float4*>(pr + f);
                float4 kv = *reinterpret_cast<const float4*>(kr + f);
                a0 = fmaf(pv.x, kv.x, a0);
                a1 = fmaf(pv.y, kv.y, a1);
                a2 = fmaf(pv.z, kv.z, a2);
                a3 = fmaf(pv.w, kv.w, a3);
            }
            float acc = biasL[o] + ((a0 + a1) + (a2 + a3));
            out[((size_t)(b * COUTn + o) << 12) + pix[pl]] = acc;
        }
        __syncthreads();
    }
}

// ---------------------------------------------------------------------------
extern "C" void kernel_launch(void* const* d_in, const int* in_sizes, int n_in,
                              void* d_out, int out_size, void* d_ws, size_t ws_size,
                              hipStream_t stream){
    const float* x    = (const float*)d_in[0];
    const float* Wh1  = (const float*)d_in[1];
    const float* bh1  = (const float*)d_in[2];
    const float* Wh2  = (const float*)d_in[3];
    const float* bh2  = (const float*)d_in[4];
    const float* Wa   = (const float*)d_in[5];
    const float* ba   = (const float*)d_in[6];
    const float* Wc   = (const float*)d_in[7];
    const float* bc   = (const float*)d_in[8];
    const float* Wo   = (const float*)d_in[9];
    const float* bo   = (const float*)d_in[10];
    const float* kern0= (const float*)d_in[11];
    const float* Wb1  = (const float*)d_in[12];
    const float* bb1  = (const float*)d_in[13];
    const float* Wb2  = (const float*)d_in[14];
    const float* bb2  = (const float*)d_in[15];
    const float* Wb3  = (const float*)d_in[16];
    const float* bb3  = (const float*)d_in[17];

    char* ws = (char*)d_ws;
    float*    feat   = (float*)(ws + 0);                         // 2,097,152 B
    float*    gcent  = (float*)(ws + 2097152);                   //    16,384 B
    u64*      gsum   = (u64*)  (ws + 2113536);                   //    98,304 B
    unsigned* gcnt   = (unsigned*)(ws + 2211840);                //     1,536 B
    int*      idx    = (int*)  (ws + 2213376);                   //    65,536 B
    int*      sorted = (int*)  (ws + 2278912);                   //    65,536 B
    int*      offs   = (int*)  (ws + 2344448);                   //       768 B
    float*    centp  = (float*)(ws + 2345216);                   //   147,456 B
    float*    wcin   = (float*)(ws + 2492672);                   //    16,384 B
    float*    warea  = (float*)(ws + 2509056);                   //     4,608 B
    float*    wcout  = (float*)(ws + 2513664);                   //    16,384 B
    float*    biasb  = (float*)(ws + 2530048);                   //    16,384 B

    float* outp = (float*)d_out;
    float* idxf = outp + (size_t)Bn * COUTn * Sn;

    k_feat<<<(Bn * CINn * Sn) / 256, 256, 0, stream>>>(x, feat, gsum, gcnt);
    for (int it = 0; it <= NITER; ++it)
        k_assign<<<Bn * 16, 256, 0, stream>>>(feat, gcent, gsum, gcnt, idx, idxf, it);
    k_sort<<<Bn, 256, 0, stream>>>(idx, sorted, offs);
    k_segsum<<<Bn * KCn, 320, 0, stream>>>(x, sorted, offs, centp);
    k_mlp<<<Bn, 512, 0, stream>>>(centp, Wh1, bh1, Wh2, bh2, Wa, ba, Wc, bc, Wo, bo,
                                  Wb1, bb1, Wb2, bb2, Wb3, bb3,
                                  wcin, warea, wcout, biasb);
    k_out<<<Bn * KCn * SPLITn, 256, 0, stream>>>(x, sorted, offs, wcin, warea, wcout,
                                                 biasb, kern0, outp);
}